// Round 1
// baseline (3549.221 us; speedup 1.0000x reference)
//
#include <hip/hip_runtime.h>
#include <math.h>

#define NN 100000
#define EE 500000

// ---------------- RTE sinusoid table [240, 256] ----------------
__global__ void rte_tab_kernel(float* __restrict__ tab) {
    int p = blockIdx.x;      // 0..239
    int j = threadIdx.x;     // 0..255
    int m = j >> 1;
    // replicate fp32 overflow: 10000^(2m) -> inf for 2m >= 10 in fp32
    float pf = (float)pow(10000.0, (double)(2 * m));
    float dv = 1.0f / (pf / 128.0f / 2.0f);
    float ang = (float)p * dv;
    const float s = 0.08838834764831845f; // 1/sqrt(128)
    float v = (j & 1) ? (cosf(ang) * s) : (sinf(ang) * s);
    tab[p * 256 + j] = v;
}

// ---------------- rte_proj[p,c] = rte_tab[p,:] @ rte_w + rte_b ----------------
__global__ void rte_proj_kernel(const float* __restrict__ tab,
                                const float* __restrict__ rte_w,
                                const float* __restrict__ rte_b,
                                float* __restrict__ proj) {
    __shared__ float row[256];
    int p = blockIdx.x;           // 240
    int c = threadIdx.x;          // 128
    for (int i = threadIdx.x; i < 256; i += 128) row[i] = tab[p * 256 + i];
    __syncthreads();
    float acc = rte_b[c];
    #pragma unroll 8
    for (int q = 0; q < 256; ++q) acc += row[q] * rte_w[q * 128 + c];
    proj[p * 128 + c] = acc;
}

// ---------------- ktab[t,p,:] = proj[p,:] @ Wk[t]; vtab likewise ----------------
__global__ void ktab_kernel(const float* __restrict__ proj,
                            const float* __restrict__ Wk,
                            const float* __restrict__ Wv,
                            float* __restrict__ ktab,
                            float* __restrict__ vtab) {
    __shared__ float row[128];
    int b = blockIdx.x;           // 720 = t*240 + p
    int t = b / 240, p = b % 240;
    int c = threadIdx.x;          // 128
    row[c] = proj[p * 128 + c];
    __syncthreads();
    const float* wk = Wk + t * 16384 + c;
    const float* wv = Wv + t * 16384 + c;
    float ak = 0.f, av = 0.f;
    #pragma unroll 8
    for (int q = 0; q < 128; ++q) {
        float rv = row[q];
        ak += rv * wk[q * 128];
        av += rv * wv[q * 128];
    }
    ktab[b * 128 + c] = ak;
    vtab[b * 128 + c] = av;
}

// ---------------- CSR build ----------------
__global__ void hist_kernel(const int* __restrict__ tgt, int* __restrict__ cnt) {
    int e = blockIdx.x * blockDim.x + threadIdx.x;
    if (e < EE) atomicAdd(&cnt[tgt[e]], 1);
}

__global__ void scan_kernel(const int* __restrict__ cnt, int* __restrict__ row_start) {
    __shared__ int sdata[1024];
    __shared__ int s_running;
    if (threadIdx.x == 0) s_running = 0;
    __syncthreads();
    for (int base = 0; base < NN; base += 1024) {
        int i = base + (int)threadIdx.x;
        int v = (i < NN) ? cnt[i] : 0;
        sdata[threadIdx.x] = v;
        __syncthreads();
        int acc = v;
        for (int off = 1; off < 1024; off <<= 1) {
            int t = (threadIdx.x >= (unsigned)off) ? sdata[threadIdx.x - off] : 0;
            __syncthreads();
            acc += t;
            sdata[threadIdx.x] = acc;
            __syncthreads();
        }
        int run = s_running;
        if (i < NN) row_start[i] = run + acc - v;   // exclusive
        __syncthreads();
        if (threadIdx.x == 1023) s_running = run + sdata[1023];
        __syncthreads();
    }
    if (threadIdx.x == 0) row_start[NN] = s_running;
}

__global__ void scatter_kernel(const int* __restrict__ tgt,
                               const int* __restrict__ row_start,
                               int* __restrict__ fill,
                               int* __restrict__ edge_id) {
    int e = blockIdx.x * blockDim.x + threadIdx.x;
    if (e < EE) {
        int t = tgt[e];
        int pos = row_start[t] + atomicAdd(&fill[t], 1);
        edge_id[pos] = e;
    }
}

// ---------------- typed linear: MODE 0 = adapt(tanh), MODE 1 = trans + skip-blend ----------------
template <int MODE>
__global__ __launch_bounds__(256) void typed_lin_kernel(
    const float* __restrict__ in, const int* __restrict__ nt,
    const float* __restrict__ W, const float* __restrict__ b,
    const float* __restrict__ skip, float* __restrict__ out) {
    __shared__ float xs[32][128];
    __shared__ int   sty[32];
    __shared__ float salpha[32];
    int nb = blockIdx.x * 32;
    const float4* xg = (const float4*)(in + (size_t)nb * 128);
    float4* xsv = (float4*)&xs[0][0];
    for (int i = threadIdx.x; i < 1024; i += 256) xsv[i] = xg[i];
    if (threadIdx.x < 32) {
        int t = nt[nb + threadIdx.x];
        sty[threadIdx.x] = t;
        if (MODE == 1) salpha[threadIdx.x] = 1.f / (1.f + __expf(-skip[t]));
    }
    __syncthreads();
    int col = threadIdx.x & 127;
    int ng  = (threadIdx.x >> 7) * 16;
    for (int ii = 0; ii < 16; ++ii) {
        int nl = ng + ii;
        int t = sty[nl];
        const float* w = W + t * 16384 + col;
        float acc = b[t * 128 + col];
        #pragma unroll 8
        for (int k = 0; k < 128; ++k) acc += xs[nl][k] * w[k * 128];
        size_t gi = (size_t)(nb + nl) * 128 + col;
        if (MODE == 0) {
            out[gi] = tanhf(acc);
        } else {
            float alpha = salpha[nl];
            out[gi] = alpha * acc + (1.f - alpha) * out[gi];
        }
    }
}

// ---------------- fused Q/K/V typed projections ----------------
__global__ __launch_bounds__(256) void qkv_kernel(
    const float* __restrict__ x, const int* __restrict__ nt,
    const float* __restrict__ Wq, const float* __restrict__ bq,
    const float* __restrict__ Wk, const float* __restrict__ bk,
    const float* __restrict__ Wv, const float* __restrict__ bv,
    float* __restrict__ Qn, float* __restrict__ Kn, float* __restrict__ Vn) {
    __shared__ float xs[32][128];
    __shared__ int   sty[32];
    int nb = blockIdx.x * 32;
    const float4* xg = (const float4*)(x + (size_t)nb * 128);
    float4* xsv = (float4*)&xs[0][0];
    for (int i = threadIdx.x; i < 1024; i += 256) xsv[i] = xg[i];
    if (threadIdx.x < 32) sty[threadIdx.x] = nt[nb + threadIdx.x];
    __syncthreads();
    int col = threadIdx.x & 127;
    int ng  = (threadIdx.x >> 7) * 16;
    for (int ii = 0; ii < 16; ++ii) {
        int nl = ng + ii;
        int t = sty[nl];
        const float* wq = Wq + t * 16384 + col;
        const float* wk = Wk + t * 16384 + col;
        const float* wv = Wv + t * 16384 + col;
        float aq = bq[t * 128 + col];
        float ak = bk[t * 128 + col];
        float av = bv[t * 128 + col];
        #pragma unroll 4
        for (int k = 0; k < 128; ++k) {
            float xv = xs[nl][k];
            aq += xv * wq[k * 128];
            ak += xv * wk[k * 128];
            av += xv * wv[k * 128];
        }
        size_t gi = (size_t)(nb + nl) * 128 + col;
        Qn[gi] = aq; Kn[gi] = ak; Vn[gi] = av;
    }
}

// ---------------- per-node attention: one wave per target node ----------------
__global__ __launch_bounds__(256) void attn_kernel(
    const float* __restrict__ Qn, const float* __restrict__ Kn, const float* __restrict__ Vn,
    const float* __restrict__ ktab, const float* __restrict__ vtab,
    const int* __restrict__ node_type, const int* __restrict__ esrc,
    const int* __restrict__ etype, const int* __restrict__ etime,
    const float* __restrict__ rel_pri, const float* __restrict__ rel_att,
    const float* __restrict__ rel_msg,
    const int* __restrict__ row_start, const int* __restrict__ edge_id,
    float* __restrict__ h_out) {
    int wave = (blockIdx.x * blockDim.x + threadIdx.x) >> 6;
    if (wave >= NN) return;
    int lane = threadIdx.x & 63;
    int n = wave;
    int d0 = lane * 2;                 // my 2 feature dims
    int h  = lane >> 3;                // head (8 lanes per head)
    int c0 = (lane & 7) * 2;           // col pair within head
    int base_lane = lane & ~7;
    int tt = node_type[n];
    float2 q = *(const float2*)(Qn + (size_t)n * 128 + d0);
    float m0 = -INFINITY, lsum = 0.f, acc0 = 0.f, acc1 = 0.f;
    int e_beg = row_start[n], e_end = row_start[n + 1];
    for (int it = e_beg; it < e_end; ++it) {
        int e   = edge_id[it];
        int src = esrc[e];
        int r   = etype[e];
        int tm  = etime[e];
        int st  = node_type[src];
        size_t tb = ((size_t)(st * 240 + tm)) * 128 + d0;
        float2 kv = *(const float2*)(Kn + (size_t)src * 128 + d0);
        float2 kt = *(const float2*)(ktab + tb);
        float2 vv = *(const float2*)(Vn + (size_t)src * 128 + d0);
        float2 vt = *(const float2*)(vtab + tb);
        float kx = kv.x + kt.x, ky = kv.y + kt.y;
        float vx = vv.x + vt.x, vy = vv.y + vt.y;
        // k2 = k[h,:] @ rel_att[r,h]  (my two output cols)
        const float* A = rel_att + (r * 8 + h) * 256;
        float k2a = 0.f, k2b = 0.f;
        #pragma unroll
        for (int i = 0; i < 16; ++i) {
            float kf = __shfl((i & 1) ? ky : kx, base_lane + (i >> 1), 64);
            k2a += kf * A[i * 16 + c0];
            k2b += kf * A[i * 16 + c0 + 1];
        }
        float sp = q.x * k2a + q.y * k2b;
        sp += __shfl_xor(sp, 1, 64);
        sp += __shfl_xor(sp, 2, 64);
        sp += __shfl_xor(sp, 4, 64);
        float pri = rel_pri[((tt * 4 + r) * 3 + st) * 8 + h];
        float s = sp * pri * 0.25f;   // 1/sqrt(16)
        // v2 = v[h,:] @ rel_msg[r,h]
        const float* M = rel_msg + (r * 8 + h) * 256;
        float v2a = 0.f, v2b = 0.f;
        #pragma unroll
        for (int i = 0; i < 16; ++i) {
            float vf = __shfl((i & 1) ? vy : vx, base_lane + (i >> 1), 64);
            v2a += vf * M[i * 16 + c0];
            v2b += vf * M[i * 16 + c0 + 1];
        }
        // online softmax (per head; s uniform across the head's 8 lanes)
        float mn = fmaxf(m0, s);
        float scale = __expf(m0 - mn);
        float p = __expf(s - mn);
        lsum = lsum * scale + p;
        acc0 = acc0 * scale + p * v2a;
        acc1 = acc1 * scale + p * v2b;
        m0 = mn;
    }
    float o0 = (lsum > 0.f) ? (acc0 / lsum) : 0.f;
    float o1 = (lsum > 0.f) ? (acc1 / lsum) : 0.f;
    // exact gelu
    o0 = 0.5f * o0 * (1.f + erff(o0 * 0.7071067811865475f));
    o1 = 0.5f * o1 * (1.f + erff(o1 * 0.7071067811865475f));
    *(float2*)(h_out + (size_t)n * 128 + d0) = make_float2(o0, o1);
}

// ---------------- launcher ----------------
extern "C" void kernel_launch(void* const* d_in, const int* in_sizes, int n_in,
                              void* d_out, int out_size, void* d_ws, size_t ws_size,
                              hipStream_t stream) {
    const float* node_feature = (const float*)d_in[0];
    const int*   node_type    = (const int*)d_in[1];
    const int*   edge_index   = (const int*)d_in[2];   // [2,E]: src then tgt
    const int*   edge_type    = (const int*)d_in[3];
    const int*   edge_time    = (const int*)d_in[4];
    const float* adapt_w      = (const float*)d_in[5];
    const float* adapt_b      = (const float*)d_in[6];
    const float* Wk           = (const float*)d_in[7];
    const float* bk           = (const float*)d_in[8];
    const float* Wq           = (const float*)d_in[9];
    const float* bq           = (const float*)d_in[10];
    const float* Wv           = (const float*)d_in[11];
    const float* bv           = (const float*)d_in[12];
    const float* Wa           = (const float*)d_in[13];
    const float* ba           = (const float*)d_in[14];
    const float* rel_pri      = (const float*)d_in[15];
    const float* rel_att      = (const float*)d_in[16];
    const float* rel_msg      = (const float*)d_in[17];
    const float* skip         = (const float*)d_in[18];
    const float* rte_w        = (const float*)d_in[19];
    const float* rte_b        = (const float*)d_in[20];
    float* out = (float*)d_out;

    const size_t ND = (size_t)NN * 128;
    float* f       = (float*)d_ws;
    float* Qn      = f;
    float* Kn      = Qn + ND;
    float* Vn      = Kn + ND;
    float* rtab    = Vn + ND;               // 240*256
    float* rproj   = rtab + 240 * 256;      // 240*128
    float* ktab    = rproj + 240 * 128;     // 3*240*128
    float* vtab    = ktab + 3 * 240 * 128;  // 3*240*128
    int*   cnt     = (int*)(vtab + 3 * 240 * 128);
    int*   fill    = cnt + NN;
    int*   row_st  = fill + NN;             // NN+1 (+pad)
    int*   edge_id = row_st + NN + 4;

    const int* esrc = edge_index;
    const int* etgt = edge_index + EE;

    // CSR build (tgt is launch-invariant; rebuilt each launch since ws is poisoned)
    hipMemsetAsync(cnt, 0, 2 * NN * sizeof(int), stream);  // cnt + fill
    rte_tab_kernel<<<240, 256, 0, stream>>>(rtab);
    hist_kernel<<<(EE + 255) / 256, 256, 0, stream>>>(etgt, cnt);
    scan_kernel<<<1, 1024, 0, stream>>>(cnt, row_st);
    scatter_kernel<<<(EE + 255) / 256, 256, 0, stream>>>(etgt, row_st, fill, edge_id);

    // input adaptation: x = tanh(typed_linear(node_feature))
    typed_lin_kernel<0><<<NN / 32, 256, 0, stream>>>(node_feature, node_type,
                                                     adapt_w, adapt_b, nullptr, out);

    for (int l = 0; l < 2; ++l) {
        const float* Wk_l = Wk + l * 49152;  const float* bk_l = bk + l * 384;
        const float* Wq_l = Wq + l * 49152;  const float* bq_l = bq + l * 384;
        const float* Wv_l = Wv + l * 49152;  const float* bv_l = bv + l * 384;
        const float* Wa_l = Wa + l * 49152;  const float* ba_l = ba + l * 384;
        const float* pri_l = rel_pri + l * 288;
        const float* att_l = rel_att + l * 8192;
        const float* msg_l = rel_msg + l * 8192;
        const float* skip_l = skip + l * 3;
        const float* rte_w_l = rte_w + l * 32768;
        const float* rte_b_l = rte_b + l * 128;

        rte_proj_kernel<<<240, 128, 0, stream>>>(rtab, rte_w_l, rte_b_l, rproj);
        ktab_kernel<<<720, 128, 0, stream>>>(rproj, Wk_l, Wv_l, ktab, vtab);
        qkv_kernel<<<NN / 32, 256, 0, stream>>>(out, node_type, Wq_l, bq_l,
                                                Wk_l, bk_l, Wv_l, bv_l, Qn, Kn, Vn);
        attn_kernel<<<NN / 4, 256, 0, stream>>>(Qn, Kn, Vn, ktab, vtab, node_type,
                                                esrc, edge_type, edge_time,
                                                pri_l, att_l, msg_l, row_st, edge_id,
                                                Qn /* h overwrites Qn: safe, row-local */);
        typed_lin_kernel<1><<<NN / 32, 256, 0, stream>>>(Qn, node_type, Wa_l, ba_l,
                                                         skip_l, out);
    }
}

// Round 2
// 2329.008 us; speedup vs baseline: 1.5239x; 1.5239x over previous
//
#include <hip/hip_runtime.h>
#include <math.h>

#define NN 100000
#define EE 500000

// ---------------- RTE sinusoid table [240, 256] ----------------
__global__ void rte_tab_kernel(float* __restrict__ tab) {
    int p = blockIdx.x;      // 0..239
    int j = threadIdx.x;     // 0..255
    int m = j >> 1;
    // replicate fp32 overflow: 10000^(2m) -> inf for 2m >= 10 in fp32
    float pf = (float)pow(10000.0, (double)(2 * m));
    float dv = 1.0f / (pf / 128.0f / 2.0f);
    float ang = (float)p * dv;
    const float s = 0.08838834764831845f; // 1/sqrt(128)
    float v = (j & 1) ? (cosf(ang) * s) : (sinf(ang) * s);
    tab[p * 256 + j] = v;
}

// ---------------- rte_proj[p,c] = rte_tab[p,:] @ rte_w + rte_b ----------------
__global__ void rte_proj_kernel(const float* __restrict__ tab,
                                const float* __restrict__ rte_w,
                                const float* __restrict__ rte_b,
                                float* __restrict__ proj) {
    __shared__ float row[256];
    int p = blockIdx.x;           // 240
    int c = threadIdx.x;          // 128
    for (int i = threadIdx.x; i < 256; i += 128) row[i] = tab[p * 256 + i];
    __syncthreads();
    float acc = rte_b[c];
    #pragma unroll 8
    for (int q = 0; q < 256; ++q) acc += row[q] * rte_w[q * 128 + c];
    proj[p * 128 + c] = acc;
}

// ---------------- ktab[t,p,:] = proj[p,:] @ Wk[t]; vtab likewise ----------------
__global__ void ktab_kernel(const float* __restrict__ proj,
                            const float* __restrict__ Wk,
                            const float* __restrict__ Wv,
                            float* __restrict__ ktab,
                            float* __restrict__ vtab) {
    __shared__ float row[128];
    int b = blockIdx.x;           // 720 = t*240 + p
    int t = b / 240, p = b % 240;
    int c = threadIdx.x;          // 128
    row[c] = proj[p * 128 + c];
    __syncthreads();
    const float* wk = Wk + t * 16384 + c;
    const float* wv = Wv + t * 16384 + c;
    float ak = 0.f, av = 0.f;
    #pragma unroll 8
    for (int q = 0; q < 128; ++q) {
        float rv = row[q];
        ak += rv * wk[q * 128];
        av += rv * wv[q * 128];
    }
    ktab[b * 128 + c] = ak;
    vtab[b * 128 + c] = av;
}

// ---------------- CSR build (edges grouped by target) ----------------
__global__ void hist_kernel(const int* __restrict__ tgt, int* __restrict__ cnt) {
    int e = blockIdx.x * blockDim.x + threadIdx.x;
    if (e < EE) atomicAdd(&cnt[tgt[e]], 1);
}

__global__ void scan_kernel(const int* __restrict__ cnt, int* __restrict__ row_start) {
    __shared__ int sdata[1024];
    __shared__ int s_running;
    if (threadIdx.x == 0) s_running = 0;
    __syncthreads();
    for (int base = 0; base < NN; base += 1024) {
        int i = base + (int)threadIdx.x;
        int v = (i < NN) ? cnt[i] : 0;
        sdata[threadIdx.x] = v;
        __syncthreads();
        int acc = v;
        for (int off = 1; off < 1024; off <<= 1) {
            int t = (threadIdx.x >= (unsigned)off) ? sdata[threadIdx.x - off] : 0;
            __syncthreads();
            acc += t;
            sdata[threadIdx.x] = acc;
            __syncthreads();
        }
        int run = s_running;
        if (i < NN) row_start[i] = run + acc - v;   // exclusive
        __syncthreads();
        if (threadIdx.x == 1023) s_running = run + sdata[1023];
        __syncthreads();
    }
    if (threadIdx.x == 0) row_start[NN] = s_running;
}

__global__ void scatter_kernel(const int* __restrict__ tgt,
                               const int* __restrict__ row_start,
                               int* __restrict__ fill,
                               int* __restrict__ edge_id) {
    int e = blockIdx.x * blockDim.x + threadIdx.x;
    if (e < EE) {
        int t = tgt[e];
        int pos = row_start[t] + atomicAdd(&fill[t], 1);
        edge_id[pos] = e;
    }
}

// ---------------- node counting sort by type (3 bins) ----------------
__global__ void node_hist_kernel(const int* __restrict__ nt, int* __restrict__ tcnt) {
    __shared__ int lc[3];
    if (threadIdx.x < 3) lc[threadIdx.x] = 0;
    __syncthreads();
    int i = blockIdx.x * blockDim.x + threadIdx.x;
    if (i < NN) atomicAdd(&lc[nt[i]], 1);
    __syncthreads();
    if (threadIdx.x < 3) atomicAdd(&tcnt[threadIdx.x], lc[threadIdx.x]);
}

__global__ void node_scatter_kernel(const int* __restrict__ nt,
                                    const int* __restrict__ tcnt,
                                    int* __restrict__ fill3,
                                    int* __restrict__ order) {
    __shared__ int lc[3], lbase[3], lfill[3];
    if (threadIdx.x < 3) { lc[threadIdx.x] = 0; lfill[threadIdx.x] = 0; }
    __syncthreads();
    int i = blockIdx.x * blockDim.x + threadIdx.x;
    int t = -1;
    if (i < NN) { t = nt[i]; atomicAdd(&lc[t], 1); }
    __syncthreads();
    if (threadIdx.x < 3) lbase[threadIdx.x] = atomicAdd(&fill3[threadIdx.x], lc[threadIdx.x]);
    __syncthreads();
    if (i < NN) {
        int rank = atomicAdd(&lfill[t], 1);
        int tb = (t == 0) ? 0 : ((t == 1) ? tcnt[0] : tcnt[0] + tcnt[1]);
        order[tb + lbase[t] + rank] = i;
    }
}

// ---------------- typed linear over type-sorted nodes ----------------
// MODE 0: out[row] = tanh(W[t] x + b[t]);  MODE 1: out[row] = a*(...)+(1-a)*out[row]
template <int MODE>
__global__ __launch_bounds__(256) void typed_lin_kernel(
    const float* __restrict__ in, const int* __restrict__ nt,
    const int* __restrict__ order,
    const float* __restrict__ W, const float* __restrict__ b,
    const float* __restrict__ skip, float* __restrict__ out) {
    __shared__ float xs[32][128];
    __shared__ int rows[32];
    __shared__ int sty[32];
    int nb = blockIdx.x * 32;
    if (threadIdx.x < 32) {
        int r = order[nb + threadIdx.x];
        rows[threadIdx.x] = r;
        sty[threadIdx.x] = nt[r];
    }
    __syncthreads();
    for (int i = threadIdx.x; i < 1024; i += 256) {
        int nl = i >> 5, e4 = i & 31;
        *(float4*)&xs[nl][e4 * 4] = *(const float4*)(in + (size_t)rows[nl] * 128 + e4 * 4);
    }
    __syncthreads();
    int col = threadIdx.x & 127;
    int ng  = (threadIdx.x >> 7) * 16;
    int t0 = sty[ng];
    bool uni = true;
    #pragma unroll
    for (int ii = 1; ii < 16; ++ii) uni &= (sty[ng + ii] == t0);
    if (uni) {
        const float* w = W + t0 * 16384 + col;
        float bv = b[t0 * 128 + col];
        float alpha = (MODE == 1) ? (1.f / (1.f + __expf(-skip[t0]))) : 0.f;
        float acc[16];
        #pragma unroll
        for (int ii = 0; ii < 16; ++ii) acc[ii] = bv;
        for (int k0 = 0; k0 < 128; k0 += 4) {
            float w0 = w[(k0 + 0) * 128];
            float w1 = w[(k0 + 1) * 128];
            float w2 = w[(k0 + 2) * 128];
            float w3 = w[(k0 + 3) * 128];
            #pragma unroll
            for (int ii = 0; ii < 16; ++ii) {
                float4 xv = *(const float4*)&xs[ng + ii][k0];
                acc[ii] += xv.x * w0 + xv.y * w1 + xv.z * w2 + xv.w * w3;
            }
        }
        #pragma unroll
        for (int ii = 0; ii < 16; ++ii) {
            size_t gi = (size_t)rows[ng + ii] * 128 + col;
            if (MODE == 0) out[gi] = tanhf(acc[ii]);
            else           out[gi] = alpha * acc[ii] + (1.f - alpha) * out[gi];
        }
    } else {
        for (int ii = 0; ii < 16; ++ii) {
            int nl = ng + ii;
            int t = sty[nl];
            const float* w = W + t * 16384 + col;
            float acc = b[t * 128 + col];
            #pragma unroll 8
            for (int k = 0; k < 128; ++k) acc += xs[nl][k] * w[k * 128];
            size_t gi = (size_t)rows[nl] * 128 + col;
            if (MODE == 0) out[gi] = tanhf(acc);
            else {
                float alpha = 1.f / (1.f + __expf(-skip[t]));
                out[gi] = alpha * acc + (1.f - alpha) * out[gi];
            }
        }
    }
}

// ---------------- fused Q/K/V typed projections over type-sorted nodes ----------------
__global__ __launch_bounds__(256) void qkv_kernel(
    const float* __restrict__ x, const int* __restrict__ nt,
    const int* __restrict__ order,
    const float* __restrict__ Wq, const float* __restrict__ bq,
    const float* __restrict__ Wk, const float* __restrict__ bk,
    const float* __restrict__ Wv, const float* __restrict__ bv,
    float* __restrict__ Qn, float* __restrict__ Kn, float* __restrict__ Vn) {
    __shared__ float xs[32][128];
    __shared__ int rows[32];
    __shared__ int sty[32];
    int nb = blockIdx.x * 32;
    if (threadIdx.x < 32) {
        int r = order[nb + threadIdx.x];
        rows[threadIdx.x] = r;
        sty[threadIdx.x] = nt[r];
    }
    __syncthreads();
    for (int i = threadIdx.x; i < 1024; i += 256) {
        int nl = i >> 5, e4 = i & 31;
        *(float4*)&xs[nl][e4 * 4] = *(const float4*)(x + (size_t)rows[nl] * 128 + e4 * 4);
    }
    __syncthreads();
    int col = threadIdx.x & 127;
    int ng  = (threadIdx.x >> 7) * 16;
    int t0 = sty[ng];
    bool uni = true;
    #pragma unroll
    for (int ii = 1; ii < 16; ++ii) uni &= (sty[ng + ii] == t0);
    if (uni) {
        const float* wq = Wq + t0 * 16384 + col;
        const float* wk = Wk + t0 * 16384 + col;
        const float* wv = Wv + t0 * 16384 + col;
        float bqv = bq[t0 * 128 + col];
        float bkv = bk[t0 * 128 + col];
        float bvv = bv[t0 * 128 + col];
        float aq[16], ak[16], av[16];
        #pragma unroll
        for (int ii = 0; ii < 16; ++ii) { aq[ii] = bqv; ak[ii] = bkv; av[ii] = bvv; }
        for (int k0 = 0; k0 < 128; k0 += 4) {
            float q0 = wq[(k0 + 0) * 128], q1 = wq[(k0 + 1) * 128];
            float q2 = wq[(k0 + 2) * 128], q3 = wq[(k0 + 3) * 128];
            float k0w = wk[(k0 + 0) * 128], k1w = wk[(k0 + 1) * 128];
            float k2w = wk[(k0 + 2) * 128], k3w = wk[(k0 + 3) * 128];
            float v0 = wv[(k0 + 0) * 128], v1 = wv[(k0 + 1) * 128];
            float v2 = wv[(k0 + 2) * 128], v3 = wv[(k0 + 3) * 128];
            #pragma unroll
            for (int ii = 0; ii < 16; ++ii) {
                float4 xv = *(const float4*)&xs[ng + ii][k0];
                aq[ii] += xv.x * q0 + xv.y * q1 + xv.z * q2 + xv.w * q3;
                ak[ii] += xv.x * k0w + xv.y * k1w + xv.z * k2w + xv.w * k3w;
                av[ii] += xv.x * v0 + xv.y * v1 + xv.z * v2 + xv.w * v3;
            }
        }
        #pragma unroll
        for (int ii = 0; ii < 16; ++ii) {
            size_t gi = (size_t)rows[ng + ii] * 128 + col;
            Qn[gi] = aq[ii]; Kn[gi] = ak[ii]; Vn[gi] = av[ii];
        }
    } else {
        for (int ii = 0; ii < 16; ++ii) {
            int nl = ng + ii;
            int t = sty[nl];
            const float* wq = Wq + t * 16384 + col;
            const float* wk = Wk + t * 16384 + col;
            const float* wv = Wv + t * 16384 + col;
            float aq = bq[t * 128 + col];
            float ak = bk[t * 128 + col];
            float av = bv[t * 128 + col];
            #pragma unroll 4
            for (int k = 0; k < 128; ++k) {
                float xv = xs[nl][k];
                aq += xv * wq[k * 128];
                ak += xv * wk[k * 128];
                av += xv * wv[k * 128];
            }
            size_t gi = (size_t)rows[nl] * 128 + col;
            Qn[gi] = aq; Kn[gi] = ak; Vn[gi] = av;
        }
    }
}

// ---------------- per-node attention: one wave per target node ----------------
__global__ __launch_bounds__(256) void attn_kernel(
    const float* __restrict__ Qn, const float* __restrict__ Kn, const float* __restrict__ Vn,
    const float* __restrict__ ktab, const float* __restrict__ vtab,
    const int* __restrict__ node_type, const int* __restrict__ esrc,
    const int* __restrict__ etype, const int* __restrict__ etime,
    const float* __restrict__ rel_pri, const float* __restrict__ rel_att,
    const float* __restrict__ rel_msg,
    const int* __restrict__ row_start, const int* __restrict__ edge_id,
    float* __restrict__ h_out) {
    int wave = (blockIdx.x * blockDim.x + threadIdx.x) >> 6;
    if (wave >= NN) return;
    int lane = threadIdx.x & 63;
    int n = wave;
    int d0 = lane * 2;                 // my 2 feature dims
    int h  = lane >> 3;                // head (8 lanes per head)
    int c0 = (lane & 7) * 2;           // col pair within head
    int base_lane = lane & ~7;
    int tt = node_type[n];
    float2 q = *(const float2*)(Qn + (size_t)n * 128 + d0);
    float m0 = -INFINITY, lsum = 0.f, acc0 = 0.f, acc1 = 0.f;
    int e_beg = row_start[n], e_end = row_start[n + 1];
    for (int it = e_beg; it < e_end; ++it) {
        int e   = edge_id[it];
        int src = esrc[e];
        int r   = etype[e];
        int tm  = etime[e];
        int st  = node_type[src];
        size_t tb = ((size_t)(st * 240 + tm)) * 128 + d0;
        float2 kv = *(const float2*)(Kn + (size_t)src * 128 + d0);
        float2 kt = *(const float2*)(ktab + tb);
        float2 vv = *(const float2*)(Vn + (size_t)src * 128 + d0);
        float2 vt = *(const float2*)(vtab + tb);
        float kx = kv.x + kt.x, ky = kv.y + kt.y;
        float vx = vv.x + vt.x, vy = vv.y + vt.y;
        // k2 = k[h,:] @ rel_att[r,h]  (my two output cols)
        const float* A = rel_att + (r * 8 + h) * 256;
        float k2a = 0.f, k2b = 0.f;
        #pragma unroll
        for (int i = 0; i < 16; ++i) {
            float kf = __shfl((i & 1) ? ky : kx, base_lane + (i >> 1), 64);
            k2a += kf * A[i * 16 + c0];
            k2b += kf * A[i * 16 + c0 + 1];
        }
        float sp = q.x * k2a + q.y * k2b;
        sp += __shfl_xor(sp, 1, 64);
        sp += __shfl_xor(sp, 2, 64);
        sp += __shfl_xor(sp, 4, 64);
        float pri = rel_pri[((tt * 4 + r) * 3 + st) * 8 + h];
        float s = sp * pri * 0.25f;   // 1/sqrt(16)
        // v2 = v[h,:] @ rel_msg[r,h]
        const float* M = rel_msg + (r * 8 + h) * 256;
        float v2a = 0.f, v2b = 0.f;
        #pragma unroll
        for (int i = 0; i < 16; ++i) {
            float vf = __shfl((i & 1) ? vy : vx, base_lane + (i >> 1), 64);
            v2a += vf * M[i * 16 + c0];
            v2b += vf * M[i * 16 + c0 + 1];
        }
        // online softmax (per head; s uniform across the head's 8 lanes)
        float mn = fmaxf(m0, s);
        float scale = __expf(m0 - mn);
        float p = __expf(s - mn);
        lsum = lsum * scale + p;
        acc0 = acc0 * scale + p * v2a;
        acc1 = acc1 * scale + p * v2b;
        m0 = mn;
    }
    float o0 = (lsum > 0.f) ? (acc0 / lsum) : 0.f;
    float o1 = (lsum > 0.f) ? (acc1 / lsum) : 0.f;
    // exact gelu
    o0 = 0.5f * o0 * (1.f + erff(o0 * 0.7071067811865475f));
    o1 = 0.5f * o1 * (1.f + erff(o1 * 0.7071067811865475f));
    *(float2*)(h_out + (size_t)n * 128 + d0) = make_float2(o0, o1);
}

// ---------------- launcher ----------------
extern "C" void kernel_launch(void* const* d_in, const int* in_sizes, int n_in,
                              void* d_out, int out_size, void* d_ws, size_t ws_size,
                              hipStream_t stream) {
    const float* node_feature = (const float*)d_in[0];
    const int*   node_type    = (const int*)d_in[1];
    const int*   edge_index   = (const int*)d_in[2];   // [2,E]: src then tgt
    const int*   edge_type    = (const int*)d_in[3];
    const int*   edge_time    = (const int*)d_in[4];
    const float* adapt_w      = (const float*)d_in[5];
    const float* adapt_b      = (const float*)d_in[6];
    const float* Wk           = (const float*)d_in[7];
    const float* bk           = (const float*)d_in[8];
    const float* Wq           = (const float*)d_in[9];
    const float* bq           = (const float*)d_in[10];
    const float* Wv           = (const float*)d_in[11];
    const float* bv           = (const float*)d_in[12];
    const float* Wa           = (const float*)d_in[13];
    const float* ba           = (const float*)d_in[14];
    const float* rel_pri      = (const float*)d_in[15];
    const float* rel_att      = (const float*)d_in[16];
    const float* rel_msg      = (const float*)d_in[17];
    const float* skip         = (const float*)d_in[18];
    const float* rte_w        = (const float*)d_in[19];
    const float* rte_b        = (const float*)d_in[20];
    float* out = (float*)d_out;

    const size_t ND = (size_t)NN * 128;
    float* f       = (float*)d_ws;
    float* Qn      = f;
    float* Kn      = Qn + ND;
    float* Vn      = Kn + ND;
    float* rtab    = Vn + ND;               // 240*256
    float* rproj   = rtab + 240 * 256;      // 240*128
    float* ktab    = rproj + 240 * 128;     // 3*240*128
    float* vtab    = ktab + 3 * 240 * 128;  // 3*240*128
    int*   cnt     = (int*)(vtab + 3 * 240 * 128);
    int*   fill    = cnt + NN;
    int*   row_st  = fill + NN;             // NN+1 (+pad)
    int*   edge_id = row_st + NN + 4;
    int*   order   = edge_id + EE;          // NN
    int*   tcnt    = order + NN;            // 3
    int*   fill3   = tcnt + 4;              // 3

    const int* esrc = edge_index;
    const int* etgt = edge_index + EE;

    // zero counters (cnt + fill contiguous; tcnt/fill3 separately)
    hipMemsetAsync(cnt, 0, 2 * NN * sizeof(int), stream);
    hipMemsetAsync(tcnt, 0, 8 * sizeof(int), stream);
    rte_tab_kernel<<<240, 256, 0, stream>>>(rtab);
    hist_kernel<<<(EE + 255) / 256, 256, 0, stream>>>(etgt, cnt);
    scan_kernel<<<1, 1024, 0, stream>>>(cnt, row_st);
    scatter_kernel<<<(EE + 255) / 256, 256, 0, stream>>>(etgt, row_st, fill, edge_id);
    node_hist_kernel<<<(NN + 255) / 256, 256, 0, stream>>>(node_type, tcnt);
    node_scatter_kernel<<<(NN + 255) / 256, 256, 0, stream>>>(node_type, tcnt, fill3, order);

    // input adaptation: x = tanh(typed_linear(node_feature))
    typed_lin_kernel<0><<<NN / 32, 256, 0, stream>>>(node_feature, node_type, order,
                                                     adapt_w, adapt_b, nullptr, out);

    for (int l = 0; l < 2; ++l) {
        const float* Wk_l = Wk + l * 49152;  const float* bk_l = bk + l * 384;
        const float* Wq_l = Wq + l * 49152;  const float* bq_l = bq + l * 384;
        const float* Wv_l = Wv + l * 49152;  const float* bv_l = bv + l * 384;
        const float* Wa_l = Wa + l * 49152;  const float* ba_l = ba + l * 384;
        const float* pri_l = rel_pri + l * 288;
        const float* att_l = rel_att + l * 8192;
        const float* msg_l = rel_msg + l * 8192;
        const float* skip_l = skip + l * 3;
        const float* rte_w_l = rte_w + l * 32768;
        const float* rte_b_l = rte_b + l * 128;

        rte_proj_kernel<<<240, 128, 0, stream>>>(rtab, rte_w_l, rte_b_l, rproj);
        ktab_kernel<<<720, 128, 0, stream>>>(rproj, Wk_l, Wv_l, ktab, vtab);
        qkv_kernel<<<NN / 32, 256, 0, stream>>>(out, node_type, order, Wq_l, bq_l,
                                                Wk_l, bk_l, Wv_l, bv_l, Qn, Kn, Vn);
        attn_kernel<<<NN / 4, 256, 0, stream>>>(Qn, Kn, Vn, ktab, vtab, node_type,
                                                esrc, edge_type, edge_time,
                                                pri_l, att_l, msg_l, row_st, edge_id,
                                                Qn /* h overwrites Qn: safe, row-local */);
        typed_lin_kernel<1><<<NN / 32, 256, 0, stream>>>(Qn, node_type, order, Wa_l, ba_l,
                                                         skip_l, out);
    }
}

// Round 3
// 2184.588 us; speedup vs baseline: 1.6247x; 1.0661x over previous
//
#include <hip/hip_runtime.h>
#include <math.h>

#define NN 100000
#define EE 500000

// ---------------- RTE sinusoid table [240, 256] ----------------
__global__ void rte_tab_kernel(float* __restrict__ tab) {
    int p = blockIdx.x;      // 0..239
    int j = threadIdx.x;     // 0..255
    int m = j >> 1;
    // replicate fp32 overflow: 10000^(2m) -> inf for 2m >= 10 in fp32
    float pf = (float)pow(10000.0, (double)(2 * m));
    float dv = 1.0f / (pf / 128.0f / 2.0f);
    float ang = (float)p * dv;
    const float s = 0.08838834764831845f; // 1/sqrt(128)
    float v = (j & 1) ? (cosf(ang) * s) : (sinf(ang) * s);
    tab[p * 256 + j] = v;
}

// ---------------- rte_proj[p,c] = rte_tab[p,:] @ rte_w + rte_b ----------------
__global__ void rte_proj_kernel(const float* __restrict__ tab,
                                const float* __restrict__ rte_w,
                                const float* __restrict__ rte_b,
                                float* __restrict__ proj) {
    __shared__ float row[256];
    int p = blockIdx.x;           // 240
    int c = threadIdx.x;          // 128
    for (int i = threadIdx.x; i < 256; i += 128) row[i] = tab[p * 256 + i];
    __syncthreads();
    float acc = rte_b[c];
    #pragma unroll 8
    for (int q = 0; q < 256; ++q) acc += row[q] * rte_w[q * 128 + c];
    proj[p * 128 + c] = acc;
}

// ---------------- ktab[t,p,:] = proj[p,:] @ Wk[t]; vtab likewise ----------------
__global__ void ktab_kernel(const float* __restrict__ proj,
                            const float* __restrict__ Wk,
                            const float* __restrict__ Wv,
                            float* __restrict__ ktab,
                            float* __restrict__ vtab) {
    __shared__ float row[128];
    int b = blockIdx.x;           // 720 = t*240 + p
    int t = b / 240, p = b % 240;
    int c = threadIdx.x;          // 128
    row[c] = proj[p * 128 + c];
    __syncthreads();
    const float* wk = Wk + t * 16384 + c;
    const float* wv = Wv + t * 16384 + c;
    float ak = 0.f, av = 0.f;
    #pragma unroll 8
    for (int q = 0; q < 128; ++q) {
        float rv = row[q];
        ak += rv * wk[q * 128];
        av += rv * wv[q * 128];
    }
    ktab[b * 128 + c] = ak;
    vtab[b * 128 + c] = av;
}

// ---------------- CSR build (edges grouped by target) ----------------
__global__ void hist_kernel(const int* __restrict__ tgt, int* __restrict__ cnt) {
    int e = blockIdx.x * blockDim.x + threadIdx.x;
    if (e < EE) atomicAdd(&cnt[tgt[e]], 1);
}

__global__ void scan_kernel(const int* __restrict__ cnt, int* __restrict__ row_start) {
    __shared__ int sdata[1024];
    __shared__ int s_running;
    if (threadIdx.x == 0) s_running = 0;
    __syncthreads();
    for (int base = 0; base < NN; base += 1024) {
        int i = base + (int)threadIdx.x;
        int v = (i < NN) ? cnt[i] : 0;
        sdata[threadIdx.x] = v;
        __syncthreads();
        int acc = v;
        for (int off = 1; off < 1024; off <<= 1) {
            int t = (threadIdx.x >= (unsigned)off) ? sdata[threadIdx.x - off] : 0;
            __syncthreads();
            acc += t;
            sdata[threadIdx.x] = acc;
            __syncthreads();
        }
        int run = s_running;
        if (i < NN) row_start[i] = run + acc - v;   // exclusive
        __syncthreads();
        if (threadIdx.x == 1023) s_running = run + sdata[1023];
        __syncthreads();
    }
    if (threadIdx.x == 0) row_start[NN] = s_running;
}

__global__ void scatter_kernel(const int* __restrict__ tgt,
                               const int* __restrict__ row_start,
                               int* __restrict__ fill,
                               int* __restrict__ edge_id) {
    int e = blockIdx.x * blockDim.x + threadIdx.x;
    if (e < EE) {
        int t = tgt[e];
        int pos = row_start[t] + atomicAdd(&fill[t], 1);
        edge_id[pos] = e;
    }
}

// ---------------- node counting sort by type (3 bins) ----------------
__global__ void node_hist_kernel(const int* __restrict__ nt, int* __restrict__ tcnt) {
    __shared__ int lc[3];
    if (threadIdx.x < 3) lc[threadIdx.x] = 0;
    __syncthreads();
    int i = blockIdx.x * blockDim.x + threadIdx.x;
    if (i < NN) atomicAdd(&lc[nt[i]], 1);
    __syncthreads();
    if (threadIdx.x < 3) atomicAdd(&tcnt[threadIdx.x], lc[threadIdx.x]);
}

__global__ void node_scatter_kernel(const int* __restrict__ nt,
                                    const int* __restrict__ tcnt,
                                    int* __restrict__ fill3,
                                    int* __restrict__ order) {
    __shared__ int lc[3], lbase[3], lfill[3];
    if (threadIdx.x < 3) { lc[threadIdx.x] = 0; lfill[threadIdx.x] = 0; }
    __syncthreads();
    int i = blockIdx.x * blockDim.x + threadIdx.x;
    int t = -1;
    if (i < NN) { t = nt[i]; atomicAdd(&lc[t], 1); }
    __syncthreads();
    if (threadIdx.x < 3) lbase[threadIdx.x] = atomicAdd(&fill3[threadIdx.x], lc[threadIdx.x]);
    __syncthreads();
    if (i < NN) {
        int rank = atomicAdd(&lfill[t], 1);
        int tb = (t == 0) ? 0 : ((t == 1) ? tcnt[0] : tcnt[0] + tcnt[1]);
        order[tb + lbase[t] + rank] = i;
    }
}

// ---------------- typed linear over type-sorted nodes ----------------
// MODE 0: out[row] = tanh(W[t] x + b[t]);  MODE 1: out[row] = a*(...)+(1-a)*out[row]
template <int MODE>
__global__ __launch_bounds__(256) void typed_lin_kernel(
    const float* __restrict__ in, const int* __restrict__ nt,
    const int* __restrict__ order,
    const float* __restrict__ W, const float* __restrict__ b,
    const float* __restrict__ skip, float* __restrict__ out) {
    __shared__ float xs[32][128];
    __shared__ int rows[32];
    __shared__ int sty[32];
    int nb = blockIdx.x * 32;
    if (threadIdx.x < 32) {
        int r = order[nb + threadIdx.x];
        rows[threadIdx.x] = r;
        sty[threadIdx.x] = nt[r];
    }
    __syncthreads();
    for (int i = threadIdx.x; i < 1024; i += 256) {
        int nl = i >> 5, e4 = i & 31;
        *(float4*)&xs[nl][e4 * 4] = *(const float4*)(in + (size_t)rows[nl] * 128 + e4 * 4);
    }
    __syncthreads();
    int col = threadIdx.x & 127;
    int ng  = (threadIdx.x >> 7) * 16;
    int t0 = sty[ng];
    bool uni = true;
    #pragma unroll
    for (int ii = 1; ii < 16; ++ii) uni &= (sty[ng + ii] == t0);
    if (uni) {
        const float* w = W + t0 * 16384 + col;
        float bv = b[t0 * 128 + col];
        float alpha = (MODE == 1) ? (1.f / (1.f + __expf(-skip[t0]))) : 0.f;
        float acc[16];
        #pragma unroll
        for (int ii = 0; ii < 16; ++ii) acc[ii] = bv;
        for (int k0 = 0; k0 < 128; k0 += 4) {
            float w0 = w[(k0 + 0) * 128];
            float w1 = w[(k0 + 1) * 128];
            float w2 = w[(k0 + 2) * 128];
            float w3 = w[(k0 + 3) * 128];
            #pragma unroll
            for (int ii = 0; ii < 16; ++ii) {
                float4 xv = *(const float4*)&xs[ng + ii][k0];
                acc[ii] += xv.x * w0 + xv.y * w1 + xv.z * w2 + xv.w * w3;
            }
        }
        #pragma unroll
        for (int ii = 0; ii < 16; ++ii) {
            size_t gi = (size_t)rows[ng + ii] * 128 + col;
            if (MODE == 0) out[gi] = tanhf(acc[ii]);
            else           out[gi] = alpha * acc[ii] + (1.f - alpha) * out[gi];
        }
    } else {
        for (int ii = 0; ii < 16; ++ii) {
            int nl = ng + ii;
            int t = sty[nl];
            const float* w = W + t * 16384 + col;
            float acc = b[t * 128 + col];
            #pragma unroll 8
            for (int k = 0; k < 128; ++k) acc += xs[nl][k] * w[k * 128];
            size_t gi = (size_t)rows[nl] * 128 + col;
            if (MODE == 0) out[gi] = tanhf(acc);
            else {
                float alpha = 1.f / (1.f + __expf(-skip[t]));
                out[gi] = alpha * acc + (1.f - alpha) * out[gi];
            }
        }
    }
}

// ---------------- fused Q/K/V typed projections over type-sorted nodes ----------------
__global__ __launch_bounds__(256) void qkv_kernel(
    const float* __restrict__ x, const int* __restrict__ nt,
    const int* __restrict__ order,
    const float* __restrict__ Wq, const float* __restrict__ bq,
    const float* __restrict__ Wk, const float* __restrict__ bk,
    const float* __restrict__ Wv, const float* __restrict__ bv,
    float* __restrict__ Qn, float* __restrict__ Kn, float* __restrict__ Vn) {
    __shared__ float xs[32][128];
    __shared__ int rows[32];
    __shared__ int sty[32];
    int nb = blockIdx.x * 32;
    if (threadIdx.x < 32) {
        int r = order[nb + threadIdx.x];
        rows[threadIdx.x] = r;
        sty[threadIdx.x] = nt[r];
    }
    __syncthreads();
    for (int i = threadIdx.x; i < 1024; i += 256) {
        int nl = i >> 5, e4 = i & 31;
        *(float4*)&xs[nl][e4 * 4] = *(const float4*)(x + (size_t)rows[nl] * 128 + e4 * 4);
    }
    __syncthreads();
    int col = threadIdx.x & 127;
    int ng  = (threadIdx.x >> 7) * 16;
    int t0 = sty[ng];
    bool uni = true;
    #pragma unroll
    for (int ii = 1; ii < 16; ++ii) uni &= (sty[ng + ii] == t0);
    if (uni) {
        const float* wq = Wq + t0 * 16384 + col;
        const float* wk = Wk + t0 * 16384 + col;
        const float* wv = Wv + t0 * 16384 + col;
        float bqv = bq[t0 * 128 + col];
        float bkv = bk[t0 * 128 + col];
        float bvv = bv[t0 * 128 + col];
        float aq[16], ak[16], av[16];
        #pragma unroll
        for (int ii = 0; ii < 16; ++ii) { aq[ii] = bqv; ak[ii] = bkv; av[ii] = bvv; }
        for (int k0 = 0; k0 < 128; k0 += 4) {
            float q0 = wq[(k0 + 0) * 128], q1 = wq[(k0 + 1) * 128];
            float q2 = wq[(k0 + 2) * 128], q3 = wq[(k0 + 3) * 128];
            float k0w = wk[(k0 + 0) * 128], k1w = wk[(k0 + 1) * 128];
            float k2w = wk[(k0 + 2) * 128], k3w = wk[(k0 + 3) * 128];
            float v0 = wv[(k0 + 0) * 128], v1 = wv[(k0 + 1) * 128];
            float v2 = wv[(k0 + 2) * 128], v3 = wv[(k0 + 3) * 128];
            #pragma unroll
            for (int ii = 0; ii < 16; ++ii) {
                float4 xv = *(const float4*)&xs[ng + ii][k0];
                aq[ii] += xv.x * q0 + xv.y * q1 + xv.z * q2 + xv.w * q3;
                ak[ii] += xv.x * k0w + xv.y * k1w + xv.z * k2w + xv.w * k3w;
                av[ii] += xv.x * v0 + xv.y * v1 + xv.z * v2 + xv.w * v3;
            }
        }
        #pragma unroll
        for (int ii = 0; ii < 16; ++ii) {
            size_t gi = (size_t)rows[ng + ii] * 128 + col;
            Qn[gi] = aq[ii]; Kn[gi] = ak[ii]; Vn[gi] = av[ii];
        }
    } else {
        for (int ii = 0; ii < 16; ++ii) {
            int nl = ng + ii;
            int t = sty[nl];
            const float* wq = Wq + t * 16384 + col;
            const float* wk = Wk + t * 16384 + col;
            const float* wv = Wv + t * 16384 + col;
            float aq = bq[t * 128 + col];
            float ak = bk[t * 128 + col];
            float av = bv[t * 128 + col];
            #pragma unroll 4
            for (int k = 0; k < 128; ++k) {
                float xv = xs[nl][k];
                aq += xv * wq[k * 128];
                ak += xv * wk[k * 128];
                av += xv * wv[k * 128];
            }
            size_t gi = (size_t)rows[nl] * 128 + col;
            Qn[gi] = aq; Kn[gi] = ak; Vn[gi] = av;
        }
    }
}

// ---------------- per-node attention: one wave per target node ----------------
// Restructured: per-node precompute qA[r] = rel_att[r,h] @ q  (score = qA·k),
// per-relation weighted-V accumulators, epilogue applies rel_msg once per node.
// Softmax without max subtraction (scores are O(1); exp cannot overflow; the
// max factor cancels in normalization).
__global__ __launch_bounds__(256) void attn_kernel(
    const float* __restrict__ Qn, const float* __restrict__ Kn, const float* __restrict__ Vn,
    const float* __restrict__ ktab, const float* __restrict__ vtab,
    const int* __restrict__ node_type, const int* __restrict__ esrc,
    const int* __restrict__ etype, const int* __restrict__ etime,
    const float* __restrict__ rel_pri, const float* __restrict__ rel_att,
    const float* __restrict__ rel_msg,
    const int* __restrict__ row_start, const int* __restrict__ edge_id,
    float* __restrict__ h_out) {
    int wave = (blockIdx.x * blockDim.x + threadIdx.x) >> 6;
    if (wave >= NN) return;
    int lane = threadIdx.x & 63;
    int n = wave;
    int d0 = lane * 2;                 // my 2 feature dims
    int h  = lane >> 3;                // head (8 lanes per head)
    int c0 = (lane & 7) * 2;           // col pair within head
    int base_lane = lane & ~7;
    int tt = node_type[n];
    int e_beg = row_start[n], e_end = row_start[n + 1];

    float2 q = *(const float2*)(Qn + (size_t)n * 128 + d0);

    // ---- prologue: qA[r][c0..c0+1] = sum_l rel_att[r,h,c0..c0+1,l] * q[h,l]
    float2 qA0 = {0.f, 0.f}, qA1 = {0.f, 0.f}, qA2 = {0.f, 0.f}, qA3 = {0.f, 0.f};
    {
        const float* pA = rel_att + h * 256 + c0 * 16;   // [r stride 2048, row stride 16]
        #pragma unroll
        for (int l = 0; l < 16; ++l) {
            float qf = __shfl((l & 1) ? q.y : q.x, base_lane + (l >> 1), 64);
            qA0.x += qf * pA[l];          qA0.y += qf * pA[16 + l];
            qA1.x += qf * pA[2048 + l];   qA1.y += qf * pA[2064 + l];
            qA2.x += qf * pA[4096 + l];   qA2.y += qf * pA[4112 + l];
            qA3.x += qf * pA[6144 + l];   qA3.y += qf * pA[6160 + l];
        }
    }

    float lsum = 0.f;
    float2 aV0 = {0.f, 0.f}, aV1 = {0.f, 0.f}, aV2 = {0.f, 0.f}, aV3 = {0.f, 0.f};
    int rmask = 0;

    for (int it = e_beg; it < e_end; ++it) {
        int e   = __builtin_amdgcn_readfirstlane(edge_id[it]);
        int src = __builtin_amdgcn_readfirstlane(esrc[e]);
        int r   = __builtin_amdgcn_readfirstlane(etype[e]);
        int tm  = __builtin_amdgcn_readfirstlane(etime[e]);
        int st  = __builtin_amdgcn_readfirstlane(node_type[src]);
        size_t tb = ((size_t)(st * 240 + tm)) * 128 + d0;
        float2 kv = *(const float2*)(Kn + (size_t)src * 128 + d0);
        float2 kt = *(const float2*)(ktab + tb);
        float2 vv = *(const float2*)(Vn + (size_t)src * 128 + d0);
        float2 vt = *(const float2*)(vtab + tb);
        float kx = kv.x + kt.x, ky = kv.y + kt.y;
        float vx = vv.x + vt.x, vy = vv.y + vt.y;
        // select qA[r] (r wave-uniform)
        float2 qa = (r == 0) ? qA0 : (r == 1) ? qA1 : (r == 2) ? qA2 : qA3;
        float sp = qa.x * kx + qa.y * ky;
        sp += __shfl_xor(sp, 1, 64);
        sp += __shfl_xor(sp, 2, 64);
        sp += __shfl_xor(sp, 4, 64);
        float pri = rel_pri[((tt * 4 + r) * 3 + st) * 8 + h];
        float p = __expf(sp * pri * 0.25f);   // 1/sqrt(16)
        lsum += p;
        rmask |= (1 << r);
        switch (r) {
            case 0: aV0.x += p * vx; aV0.y += p * vy; break;
            case 1: aV1.x += p * vx; aV1.y += p * vy; break;
            case 2: aV2.x += p * vx; aV2.y += p * vy; break;
            default: aV3.x += p * vx; aV3.y += p * vy; break;
        }
    }

    // ---- epilogue: o[c0..c0+1] = sum_r sum_i aV[r][i] * rel_msg[r,h,i,c0..c0+1]
    float o0 = 0.f, o1 = 0.f;
    rmask = __builtin_amdgcn_readfirstlane(rmask);
    const float* pM = rel_msg + h * 256 + c0;   // [r stride 2048, i stride 16]
    if (rmask & 1) {
        #pragma unroll
        for (int i = 0; i < 16; ++i) {
            float vf = __shfl((i & 1) ? aV0.y : aV0.x, base_lane + (i >> 1), 64);
            o0 += vf * pM[i * 16]; o1 += vf * pM[i * 16 + 1];
        }
    }
    if (rmask & 2) {
        #pragma unroll
        for (int i = 0; i < 16; ++i) {
            float vf = __shfl((i & 1) ? aV1.y : aV1.x, base_lane + (i >> 1), 64);
            o0 += vf * pM[2048 + i * 16]; o1 += vf * pM[2048 + i * 16 + 1];
        }
    }
    if (rmask & 4) {
        #pragma unroll
        for (int i = 0; i < 16; ++i) {
            float vf = __shfl((i & 1) ? aV2.y : aV2.x, base_lane + (i >> 1), 64);
            o0 += vf * pM[4096 + i * 16]; o1 += vf * pM[4096 + i * 16 + 1];
        }
    }
    if (rmask & 8) {
        #pragma unroll
        for (int i = 0; i < 16; ++i) {
            float vf = __shfl((i & 1) ? aV3.y : aV3.x, base_lane + (i >> 1), 64);
            o0 += vf * pM[6144 + i * 16]; o1 += vf * pM[6144 + i * 16 + 1];
        }
    }
    if (lsum > 0.f) { o0 /= lsum; o1 /= lsum; }
    // exact gelu
    o0 = 0.5f * o0 * (1.f + erff(o0 * 0.7071067811865475f));
    o1 = 0.5f * o1 * (1.f + erff(o1 * 0.7071067811865475f));
    *(float2*)(h_out + (size_t)n * 128 + d0) = make_float2(o0, o1);
}

// ---------------- launcher ----------------
extern "C" void kernel_launch(void* const* d_in, const int* in_sizes, int n_in,
                              void* d_out, int out_size, void* d_ws, size_t ws_size,
                              hipStream_t stream) {
    const float* node_feature = (const float*)d_in[0];
    const int*   node_type    = (const int*)d_in[1];
    const int*   edge_index   = (const int*)d_in[2];   // [2,E]: src then tgt
    const int*   edge_type    = (const int*)d_in[3];
    const int*   edge_time    = (const int*)d_in[4];
    const float* adapt_w      = (const float*)d_in[5];
    const float* adapt_b      = (const float*)d_in[6];
    const float* Wk           = (const float*)d_in[7];
    const float* bk           = (const float*)d_in[8];
    const float* Wq           = (const float*)d_in[9];
    const float* bq           = (const float*)d_in[10];
    const float* Wv           = (const float*)d_in[11];
    const float* bv           = (const float*)d_in[12];
    const float* Wa           = (const float*)d_in[13];
    const float* ba           = (const float*)d_in[14];
    const float* rel_pri      = (const float*)d_in[15];
    const float* rel_att      = (const float*)d_in[16];
    const float* rel_msg      = (const float*)d_in[17];
    const float* skip         = (const float*)d_in[18];
    const float* rte_w        = (const float*)d_in[19];
    const float* rte_b        = (const float*)d_in[20];
    float* out = (float*)d_out;

    const size_t ND = (size_t)NN * 128;
    float* f       = (float*)d_ws;
    float* Qn      = f;
    float* Kn      = Qn + ND;
    float* Vn      = Kn + ND;
    float* rtab    = Vn + ND;               // 240*256
    float* rproj   = rtab + 240 * 256;      // 240*128
    float* ktab    = rproj + 240 * 128;     // 3*240*128
    float* vtab    = ktab + 3 * 240 * 128;  // 3*240*128
    int*   cnt     = (int*)(vtab + 3 * 240 * 128);
    int*   fill    = cnt + NN;
    int*   row_st  = fill + NN;             // NN+1 (+pad)
    int*   edge_id = row_st + NN + 4;
    int*   order   = edge_id + EE;          // NN
    int*   tcnt    = order + NN;            // 3
    int*   fill3   = tcnt + 4;              // 3

    const int* esrc = edge_index;
    const int* etgt = edge_index + EE;

    // zero counters (cnt + fill contiguous; tcnt/fill3 separately)
    hipMemsetAsync(cnt, 0, 2 * NN * sizeof(int), stream);
    hipMemsetAsync(tcnt, 0, 8 * sizeof(int), stream);
    rte_tab_kernel<<<240, 256, 0, stream>>>(rtab);
    hist_kernel<<<(EE + 255) / 256, 256, 0, stream>>>(etgt, cnt);
    scan_kernel<<<1, 1024, 0, stream>>>(cnt, row_st);
    scatter_kernel<<<(EE + 255) / 256, 256, 0, stream>>>(etgt, row_st, fill, edge_id);
    node_hist_kernel<<<(NN + 255) / 256, 256, 0, stream>>>(node_type, tcnt);
    node_scatter_kernel<<<(NN + 255) / 256, 256, 0, stream>>>(node_type, tcnt, fill3, order);

    // input adaptation: x = tanh(typed_linear(node_feature))
    typed_lin_kernel<0><<<NN / 32, 256, 0, stream>>>(node_feature, node_type, order,
                                                     adapt_w, adapt_b, nullptr, out);

    for (int l = 0; l < 2; ++l) {
        const float* Wk_l = Wk + l * 49152;  const float* bk_l = bk + l * 384;
        const float* Wq_l = Wq + l * 49152;  const float* bq_l = bq + l * 384;
        const float* Wv_l = Wv + l * 49152;  const float* bv_l = bv + l * 384;
        const float* Wa_l = Wa + l * 49152;  const float* ba_l = ba + l * 384;
        const float* pri_l = rel_pri + l * 288;
        const float* att_l = rel_att + l * 8192;
        const float* msg_l = rel_msg + l * 8192;
        const float* skip_l = skip + l * 3;
        const float* rte_w_l = rte_w + l * 32768;
        const float* rte_b_l = rte_b + l * 128;

        rte_proj_kernel<<<240, 128, 0, stream>>>(rtab, rte_w_l, rte_b_l, rproj);
        ktab_kernel<<<720, 128, 0, stream>>>(rproj, Wk_l, Wv_l, ktab, vtab);
        qkv_kernel<<<NN / 32, 256, 0, stream>>>(out, node_type, order, Wq_l, bq_l,
                                                Wk_l, bk_l, Wv_l, bv_l, Qn, Kn, Vn);
        attn_kernel<<<NN / 4, 256, 0, stream>>>(Qn, Kn, Vn, ktab, vtab, node_type,
                                                esrc, edge_type, edge_time,
                                                pri_l, att_l, msg_l, row_st, edge_id,
                                                Qn /* h overwrites Qn: safe, row-local */);
        typed_lin_kernel<1><<<NN / 32, 256, 0, stream>>>(Qn, node_type, order, Wa_l, ba_l,
                                                         skip_l, out);
    }
}

// Round 4
// 2167.084 us; speedup vs baseline: 1.6378x; 1.0081x over previous
//
#include <hip/hip_runtime.h>
#include <math.h>

#define NN 100000
#define EE 500000

// ---------------- RTE sinusoid table [240, 256] ----------------
__global__ void rte_tab_kernel(float* __restrict__ tab) {
    int p = blockIdx.x;      // 0..239
    int j = threadIdx.x;     // 0..255
    int m = j >> 1;
    // replicate fp32 overflow: 10000^(2m) -> inf for 2m >= 10 in fp32
    float pf = (float)pow(10000.0, (double)(2 * m));
    float dv = 1.0f / (pf / 128.0f / 2.0f);
    float ang = (float)p * dv;
    const float s = 0.08838834764831845f; // 1/sqrt(128)
    float v = (j & 1) ? (cosf(ang) * s) : (sinf(ang) * s);
    tab[p * 256 + j] = v;
}

// ---------------- rte_proj[p,c] = rte_tab[p,:] @ rte_w + rte_b ----------------
__global__ void rte_proj_kernel(const float* __restrict__ tab,
                                const float* __restrict__ rte_w,
                                const float* __restrict__ rte_b,
                                float* __restrict__ proj) {
    __shared__ float row[256];
    int p = blockIdx.x;           // 240
    int c = threadIdx.x;          // 128
    for (int i = threadIdx.x; i < 256; i += 128) row[i] = tab[p * 256 + i];
    __syncthreads();
    float acc = rte_b[c];
    #pragma unroll 8
    for (int q = 0; q < 256; ++q) acc += row[q] * rte_w[q * 128 + c];
    proj[p * 128 + c] = acc;
}

// ---------------- ktv[b][0:128]=proj@Wk[t], ktv[b][128:256]=proj@Wv[t] ----------------
__global__ void ktv_kernel(const float* __restrict__ proj,
                           const float* __restrict__ Wk,
                           const float* __restrict__ Wv,
                           float* __restrict__ ktv) {
    __shared__ float row[128];
    int b = blockIdx.x;           // 720 = t*240 + p
    int t = b / 240, p = b % 240;
    int c = threadIdx.x;          // 128
    row[c] = proj[p * 128 + c];
    __syncthreads();
    const float* wk = Wk + t * 16384 + c;
    const float* wv = Wv + t * 16384 + c;
    float ak = 0.f, av = 0.f;
    #pragma unroll 8
    for (int q = 0; q < 128; ++q) {
        float rv = row[q];
        ak += rv * wk[q * 128];
        av += rv * wv[q * 128];
    }
    ktv[(size_t)b * 256 + c] = ak;
    ktv[(size_t)b * 256 + 128 + c] = av;
}

// ---------------- CSR build (edges grouped by target) ----------------
__global__ void hist_kernel(const int* __restrict__ tgt, int* __restrict__ cnt) {
    int e = blockIdx.x * blockDim.x + threadIdx.x;
    if (e < EE) atomicAdd(&cnt[tgt[e]], 1);
}

__global__ void scan_kernel(const int* __restrict__ cnt, int* __restrict__ row_start) {
    __shared__ int sdata[1024];
    __shared__ int s_running;
    if (threadIdx.x == 0) s_running = 0;
    __syncthreads();
    for (int base = 0; base < NN; base += 1024) {
        int i = base + (int)threadIdx.x;
        int v = (i < NN) ? cnt[i] : 0;
        sdata[threadIdx.x] = v;
        __syncthreads();
        int acc = v;
        for (int off = 1; off < 1024; off <<= 1) {
            int t = (threadIdx.x >= (unsigned)off) ? sdata[threadIdx.x - off] : 0;
            __syncthreads();
            acc += t;
            sdata[threadIdx.x] = acc;
            __syncthreads();
        }
        int run = s_running;
        if (i < NN) row_start[i] = run + acc - v;   // exclusive
        __syncthreads();
        if (threadIdx.x == 1023) s_running = run + sdata[1023];
        __syncthreads();
    }
    if (threadIdx.x == 0) row_start[NN] = s_running;
}

__global__ void scatter_kernel(const int* __restrict__ tgt,
                               const int* __restrict__ row_start,
                               int* __restrict__ fill,
                               int* __restrict__ edge_id) {
    int e = blockIdx.x * blockDim.x + threadIdx.x;
    if (e < EE) {
        int t = tgt[e];
        int pos = row_start[t] + atomicAdd(&fill[t], 1);
        edge_id[pos] = e;
    }
}

// ---------------- edge meta resolve (edge-parallel; hides gather latency via TLP) ----------------
// meta[it] = {src, (tabrow<<4) | (st<<2) | r} with tabrow = st*240+tm
__global__ void edge_meta_kernel(const int* __restrict__ esrc,
                                 const int* __restrict__ etype,
                                 const int* __restrict__ etime,
                                 const int* __restrict__ node_type,
                                 const int* __restrict__ edge_id,
                                 int2* __restrict__ meta) {
    int it = blockIdx.x * blockDim.x + threadIdx.x;
    if (it < EE) {
        int e = edge_id[it];
        int src = esrc[e];
        int r = etype[e];
        int tm = etime[e];
        int st = node_type[src];
        int tabrow = st * 240 + tm;
        meta[it] = make_int2(src, (tabrow << 4) | (st << 2) | r);
    }
}

// ---------------- node counting sort by type (3 bins) ----------------
__global__ void node_hist_kernel(const int* __restrict__ nt, int* __restrict__ tcnt) {
    __shared__ int lc[3];
    if (threadIdx.x < 3) lc[threadIdx.x] = 0;
    __syncthreads();
    int i = blockIdx.x * blockDim.x + threadIdx.x;
    if (i < NN) atomicAdd(&lc[nt[i]], 1);
    __syncthreads();
    if (threadIdx.x < 3) atomicAdd(&tcnt[threadIdx.x], lc[threadIdx.x]);
}

__global__ void node_scatter_kernel(const int* __restrict__ nt,
                                    const int* __restrict__ tcnt,
                                    int* __restrict__ fill3,
                                    int* __restrict__ order) {
    __shared__ int lc[3], lbase[3], lfill[3];
    if (threadIdx.x < 3) { lc[threadIdx.x] = 0; lfill[threadIdx.x] = 0; }
    __syncthreads();
    int i = blockIdx.x * blockDim.x + threadIdx.x;
    int t = -1;
    if (i < NN) { t = nt[i]; atomicAdd(&lc[t], 1); }
    __syncthreads();
    if (threadIdx.x < 3) lbase[threadIdx.x] = atomicAdd(&fill3[threadIdx.x], lc[threadIdx.x]);
    __syncthreads();
    if (i < NN) {
        int rank = atomicAdd(&lfill[t], 1);
        int tb = (t == 0) ? 0 : ((t == 1) ? tcnt[0] : tcnt[0] + tcnt[1]);
        order[tb + lbase[t] + rank] = i;
    }
}

// ---------------- typed linear over type-sorted nodes ----------------
// MODE 0: out[row] = tanh(W[t] x + b[t]);  MODE 1: out[row] = a*(...)+(1-a)*out[row]
template <int MODE>
__global__ __launch_bounds__(256) void typed_lin_kernel(
    const float* __restrict__ in, const int* __restrict__ nt,
    const int* __restrict__ order,
    const float* __restrict__ W, const float* __restrict__ b,
    const float* __restrict__ skip, float* __restrict__ out) {
    __shared__ float xs[32][128];
    __shared__ int rows[32];
    __shared__ int sty[32];
    int nb = blockIdx.x * 32;
    if (threadIdx.x < 32) {
        int r = order[nb + threadIdx.x];
        rows[threadIdx.x] = r;
        sty[threadIdx.x] = nt[r];
    }
    __syncthreads();
    for (int i = threadIdx.x; i < 1024; i += 256) {
        int nl = i >> 5, e4 = i & 31;
        *(float4*)&xs[nl][e4 * 4] = *(const float4*)(in + (size_t)rows[nl] * 128 + e4 * 4);
    }
    __syncthreads();
    int col = threadIdx.x & 127;
    int ng  = (threadIdx.x >> 7) * 16;
    int t0 = sty[ng];
    bool uni = true;
    #pragma unroll
    for (int ii = 1; ii < 16; ++ii) uni &= (sty[ng + ii] == t0);
    if (uni) {
        const float* w = W + t0 * 16384 + col;
        float bv = b[t0 * 128 + col];
        float alpha = (MODE == 1) ? (1.f / (1.f + __expf(-skip[t0]))) : 0.f;
        float acc[16];
        #pragma unroll
        for (int ii = 0; ii < 16; ++ii) acc[ii] = bv;
        for (int k0 = 0; k0 < 128; k0 += 4) {
            float w0 = w[(k0 + 0) * 128];
            float w1 = w[(k0 + 1) * 128];
            float w2 = w[(k0 + 2) * 128];
            float w3 = w[(k0 + 3) * 128];
            #pragma unroll
            for (int ii = 0; ii < 16; ++ii) {
                float4 xv = *(const float4*)&xs[ng + ii][k0];
                acc[ii] += xv.x * w0 + xv.y * w1 + xv.z * w2 + xv.w * w3;
            }
        }
        #pragma unroll
        for (int ii = 0; ii < 16; ++ii) {
            size_t gi = (size_t)rows[ng + ii] * 128 + col;
            if (MODE == 0) out[gi] = tanhf(acc[ii]);
            else           out[gi] = alpha * acc[ii] + (1.f - alpha) * out[gi];
        }
    } else {
        for (int ii = 0; ii < 16; ++ii) {
            int nl = ng + ii;
            int t = sty[nl];
            const float* w = W + t * 16384 + col;
            float acc = b[t * 128 + col];
            #pragma unroll 8
            for (int k = 0; k < 128; ++k) acc += xs[nl][k] * w[k * 128];
            size_t gi = (size_t)rows[nl] * 128 + col;
            if (MODE == 0) out[gi] = tanhf(acc);
            else {
                float alpha = 1.f / (1.f + __expf(-skip[t]));
                out[gi] = alpha * acc + (1.f - alpha) * out[gi];
            }
        }
    }
}

// ---------------- fused Q/K/V typed projections; K/V interleaved per row ----------------
__global__ __launch_bounds__(256) void qkv_kernel(
    const float* __restrict__ x, const int* __restrict__ nt,
    const int* __restrict__ order,
    const float* __restrict__ Wq, const float* __restrict__ bq,
    const float* __restrict__ Wk, const float* __restrict__ bk,
    const float* __restrict__ Wv, const float* __restrict__ bv,
    float* __restrict__ Qn, float* __restrict__ KV) {
    __shared__ float xs[32][128];
    __shared__ int rows[32];
    __shared__ int sty[32];
    int nb = blockIdx.x * 32;
    if (threadIdx.x < 32) {
        int r = order[nb + threadIdx.x];
        rows[threadIdx.x] = r;
        sty[threadIdx.x] = nt[r];
    }
    __syncthreads();
    for (int i = threadIdx.x; i < 1024; i += 256) {
        int nl = i >> 5, e4 = i & 31;
        *(float4*)&xs[nl][e4 * 4] = *(const float4*)(x + (size_t)rows[nl] * 128 + e4 * 4);
    }
    __syncthreads();
    int col = threadIdx.x & 127;
    int ng  = (threadIdx.x >> 7) * 16;
    int t0 = sty[ng];
    bool uni = true;
    #pragma unroll
    for (int ii = 1; ii < 16; ++ii) uni &= (sty[ng + ii] == t0);
    if (uni) {
        const float* wq = Wq + t0 * 16384 + col;
        const float* wk = Wk + t0 * 16384 + col;
        const float* wv = Wv + t0 * 16384 + col;
        float bqv = bq[t0 * 128 + col];
        float bkv = bk[t0 * 128 + col];
        float bvv = bv[t0 * 128 + col];
        float aq[16], ak[16], av[16];
        #pragma unroll
        for (int ii = 0; ii < 16; ++ii) { aq[ii] = bqv; ak[ii] = bkv; av[ii] = bvv; }
        for (int k0 = 0; k0 < 128; k0 += 4) {
            float q0 = wq[(k0 + 0) * 128], q1 = wq[(k0 + 1) * 128];
            float q2 = wq[(k0 + 2) * 128], q3 = wq[(k0 + 3) * 128];
            float k0w = wk[(k0 + 0) * 128], k1w = wk[(k0 + 1) * 128];
            float k2w = wk[(k0 + 2) * 128], k3w = wk[(k0 + 3) * 128];
            float v0 = wv[(k0 + 0) * 128], v1 = wv[(k0 + 1) * 128];
            float v2 = wv[(k0 + 2) * 128], v3 = wv[(k0 + 3) * 128];
            #pragma unroll
            for (int ii = 0; ii < 16; ++ii) {
                float4 xv = *(const float4*)&xs[ng + ii][k0];
                aq[ii] += xv.x * q0 + xv.y * q1 + xv.z * q2 + xv.w * q3;
                ak[ii] += xv.x * k0w + xv.y * k1w + xv.z * k2w + xv.w * k3w;
                av[ii] += xv.x * v0 + xv.y * v1 + xv.z * v2 + xv.w * v3;
            }
        }
        #pragma unroll
        for (int ii = 0; ii < 16; ++ii) {
            size_t row = (size_t)rows[ng + ii];
            Qn[row * 128 + col] = aq[ii];
            KV[row * 256 + col] = ak[ii];
            KV[row * 256 + 128 + col] = av[ii];
        }
    } else {
        for (int ii = 0; ii < 16; ++ii) {
            int nl = ng + ii;
            int t = sty[nl];
            const float* wq = Wq + t * 16384 + col;
            const float* wk = Wk + t * 16384 + col;
            const float* wv = Wv + t * 16384 + col;
            float aq = bq[t * 128 + col];
            float ak = bk[t * 128 + col];
            float av = bv[t * 128 + col];
            #pragma unroll 4
            for (int k = 0; k < 128; ++k) {
                float xv = xs[nl][k];
                aq += xv * wq[k * 128];
                ak += xv * wk[k * 128];
                av += xv * wv[k * 128];
            }
            size_t row = (size_t)rows[nl];
            Qn[row * 128 + col] = aq;
            KV[row * 256 + col] = ak;
            KV[row * 256 + 128 + col] = av;
        }
    }
}

// ---------------- per-node attention: one wave per target node ----------------
// Edge meta pre-resolved (coalesced stream); only K/V row gathers remain in loop,
// unrolled x2 so two edges' gathers are in flight per wait.
__global__ __launch_bounds__(256) void attn_kernel(
    const float* __restrict__ Qn, const float* __restrict__ KV,
    const float* __restrict__ ktv,
    const int* __restrict__ node_type, const int2* __restrict__ meta,
    const float* __restrict__ rel_pri, const float* __restrict__ rel_att,
    const float* __restrict__ rel_msg,
    const int* __restrict__ row_start, float* __restrict__ h_out) {
    int wave = (blockIdx.x * blockDim.x + threadIdx.x) >> 6;
    if (wave >= NN) return;
    int lane = threadIdx.x & 63;
    int n = wave;
    int d0 = lane * 2;                 // my 2 feature dims
    int h  = lane >> 3;                // head (8 lanes per head)
    int c0 = (lane & 7) * 2;           // col pair within head
    int base_lane = lane & ~7;
    int tt = node_type[n];
    int e_beg = row_start[n], e_end = row_start[n + 1];

    float2 q = *(const float2*)(Qn + (size_t)n * 128 + d0);

    // ---- prologue: qA[r][c0..c0+1] = sum_l rel_att[r,h,c0..c0+1,l] * q[h,l]
    float2 qA0 = {0.f, 0.f}, qA1 = {0.f, 0.f}, qA2 = {0.f, 0.f}, qA3 = {0.f, 0.f};
    {
        const float* pA = rel_att + h * 256 + c0 * 16;   // [r stride 2048, row stride 16]
        #pragma unroll
        for (int l = 0; l < 16; ++l) {
            float qf = __shfl((l & 1) ? q.y : q.x, base_lane + (l >> 1), 64);
            qA0.x += qf * pA[l];          qA0.y += qf * pA[16 + l];
            qA1.x += qf * pA[2048 + l];   qA1.y += qf * pA[2064 + l];
            qA2.x += qf * pA[4096 + l];   qA2.y += qf * pA[4112 + l];
            qA3.x += qf * pA[6144 + l];   qA3.y += qf * pA[6160 + l];
        }
    }

    float lsum = 0.f;
    float2 aV0 = {0.f, 0.f}, aV1 = {0.f, 0.f}, aV2 = {0.f, 0.f}, aV3 = {0.f, 0.f};
    int rmask = 0;
    const float* pri_t = rel_pri + tt * 96 + h;   // + (r*3+st)*8

    for (int cb = e_beg; cb < e_end; cb += 64) {
        int cdeg = min(64, e_end - cb);
        int2 mm = (cb + lane < e_end) ? meta[cb + lane] : make_int2(0, 0);
        int mx = mm.x, my = mm.y;
        int i = 0;
        for (; i + 2 <= cdeg; i += 2) {
            int srcA  = __shfl(mx, i, 64);
            int codeA = __shfl(my, i, 64);
            int srcB  = __shfl(mx, i + 1, 64);
            int codeB = __shfl(my, i + 1, 64);
            int rA = codeA & 3, stA = (codeA >> 2) & 3, tbA = codeA >> 4;
            int rB = codeB & 3, stB = (codeB >> 2) & 3, tbB = codeB >> 4;
            const float* kvA = KV + (size_t)srcA * 256 + d0;
            const float* ktA = ktv + (size_t)tbA * 256 + d0;
            const float* kvB = KV + (size_t)srcB * 256 + d0;
            const float* ktB = ktv + (size_t)tbB * 256 + d0;
            float2 k1A = *(const float2*)kvA;
            float2 k2A = *(const float2*)ktA;
            float2 v1A = *(const float2*)(kvA + 128);
            float2 v2A = *(const float2*)(ktA + 128);
            float2 k1B = *(const float2*)kvB;
            float2 k2B = *(const float2*)ktB;
            float2 v1B = *(const float2*)(kvB + 128);
            float2 v2B = *(const float2*)(ktB + 128);
            float priA = pri_t[(rA * 3 + stA) * 8];
            float priB = pri_t[(rB * 3 + stB) * 8];
            float kxA = k1A.x + k2A.x, kyA = k1A.y + k2A.y;
            float kxB = k1B.x + k2B.x, kyB = k1B.y + k2B.y;
            float2 qaA = (rA == 0) ? qA0 : (rA == 1) ? qA1 : (rA == 2) ? qA2 : qA3;
            float2 qaB = (rB == 0) ? qA0 : (rB == 1) ? qA1 : (rB == 2) ? qA2 : qA3;
            float spA = qaA.x * kxA + qaA.y * kyA;
            float spB = qaB.x * kxB + qaB.y * kyB;
            spA += __shfl_xor(spA, 1, 64);
            spB += __shfl_xor(spB, 1, 64);
            spA += __shfl_xor(spA, 2, 64);
            spB += __shfl_xor(spB, 2, 64);
            spA += __shfl_xor(spA, 4, 64);
            spB += __shfl_xor(spB, 4, 64);
            float pA = __expf(spA * priA * 0.25f);
            float pB = __expf(spB * priB * 0.25f);
            lsum += pA + pB;
            rmask |= (1 << rA) | (1 << rB);
            float vxA = v1A.x + v2A.x, vyA = v1A.y + v2A.y;
            float vxB = v1B.x + v2B.x, vyB = v1B.y + v2B.y;
            switch (rA) {
                case 0: aV0.x += pA * vxA; aV0.y += pA * vyA; break;
                case 1: aV1.x += pA * vxA; aV1.y += pA * vyA; break;
                case 2: aV2.x += pA * vxA; aV2.y += pA * vyA; break;
                default: aV3.x += pA * vxA; aV3.y += pA * vyA; break;
            }
            switch (rB) {
                case 0: aV0.x += pB * vxB; aV0.y += pB * vyB; break;
                case 1: aV1.x += pB * vxB; aV1.y += pB * vyB; break;
                case 2: aV2.x += pB * vxB; aV2.y += pB * vyB; break;
                default: aV3.x += pB * vxB; aV3.y += pB * vyB; break;
            }
        }
        if (i < cdeg) {
            int srcA  = __shfl(mx, i, 64);
            int codeA = __shfl(my, i, 64);
            int rA = codeA & 3, stA = (codeA >> 2) & 3, tbA = codeA >> 4;
            const float* kvA = KV + (size_t)srcA * 256 + d0;
            const float* ktA = ktv + (size_t)tbA * 256 + d0;
            float2 k1A = *(const float2*)kvA;
            float2 k2A = *(const float2*)ktA;
            float2 v1A = *(const float2*)(kvA + 128);
            float2 v2A = *(const float2*)(ktA + 128);
            float priA = pri_t[(rA * 3 + stA) * 8];
            float kxA = k1A.x + k2A.x, kyA = k1A.y + k2A.y;
            float2 qaA = (rA == 0) ? qA0 : (rA == 1) ? qA1 : (rA == 2) ? qA2 : qA3;
            float spA = qaA.x * kxA + qaA.y * kyA;
            spA += __shfl_xor(spA, 1, 64);
            spA += __shfl_xor(spA, 2, 64);
            spA += __shfl_xor(spA, 4, 64);
            float pA = __expf(spA * priA * 0.25f);
            lsum += pA;
            rmask |= (1 << rA);
            float vxA = v1A.x + v2A.x, vyA = v1A.y + v2A.y;
            switch (rA) {
                case 0: aV0.x += pA * vxA; aV0.y += pA * vyA; break;
                case 1: aV1.x += pA * vxA; aV1.y += pA * vyA; break;
                case 2: aV2.x += pA * vxA; aV2.y += pA * vyA; break;
                default: aV3.x += pA * vxA; aV3.y += pA * vyA; break;
            }
        }
    }

    // ---- epilogue: o[c0..c0+1] = sum_r sum_i aV[r][i] * rel_msg[r,h,i,c0..c0+1]
    float o0 = 0.f, o1 = 0.f;
    rmask = __builtin_amdgcn_readfirstlane(rmask);
    const float* pM = rel_msg + h * 256 + c0;   // [r stride 2048, i stride 16]
    if (rmask & 1) {
        #pragma unroll
        for (int i = 0; i < 16; ++i) {
            float vf = __shfl((i & 1) ? aV0.y : aV0.x, base_lane + (i >> 1), 64);
            o0 += vf * pM[i * 16]; o1 += vf * pM[i * 16 + 1];
        }
    }
    if (rmask & 2) {
        #pragma unroll
        for (int i = 0; i < 16; ++i) {
            float vf = __shfl((i & 1) ? aV1.y : aV1.x, base_lane + (i >> 1), 64);
            o0 += vf * pM[2048 + i * 16]; o1 += vf * pM[2048 + i * 16 + 1];
        }
    }
    if (rmask & 4) {
        #pragma unroll
        for (int i = 0; i < 16; ++i) {
            float vf = __shfl((i & 1) ? aV2.y : aV2.x, base_lane + (i >> 1), 64);
            o0 += vf * pM[4096 + i * 16]; o1 += vf * pM[4096 + i * 16 + 1];
        }
    }
    if (rmask & 8) {
        #pragma unroll
        for (int i = 0; i < 16; ++i) {
            float vf = __shfl((i & 1) ? aV3.y : aV3.x, base_lane + (i >> 1), 64);
            o0 += vf * pM[6144 + i * 16]; o1 += vf * pM[6144 + i * 16 + 1];
        }
    }
    if (lsum > 0.f) { o0 /= lsum; o1 /= lsum; }
    // exact gelu
    o0 = 0.5f * o0 * (1.f + erff(o0 * 0.7071067811865475f));
    o1 = 0.5f * o1 * (1.f + erff(o1 * 0.7071067811865475f));
    *(float2*)(h_out + (size_t)n * 128 + d0) = make_float2(o0, o1);
}

// ---------------- launcher ----------------
extern "C" void kernel_launch(void* const* d_in, const int* in_sizes, int n_in,
                              void* d_out, int out_size, void* d_ws, size_t ws_size,
                              hipStream_t stream) {
    const float* node_feature = (const float*)d_in[0];
    const int*   node_type    = (const int*)d_in[1];
    const int*   edge_index   = (const int*)d_in[2];   // [2,E]: src then tgt
    const int*   edge_type    = (const int*)d_in[3];
    const int*   edge_time    = (const int*)d_in[4];
    const float* adapt_w      = (const float*)d_in[5];
    const float* adapt_b      = (const float*)d_in[6];
    const float* Wk           = (const float*)d_in[7];
    const float* bk           = (const float*)d_in[8];
    const float* Wq           = (const float*)d_in[9];
    const float* bq           = (const float*)d_in[10];
    const float* Wv           = (const float*)d_in[11];
    const float* bv           = (const float*)d_in[12];
    const float* Wa           = (const float*)d_in[13];
    const float* ba           = (const float*)d_in[14];
    const float* rel_pri      = (const float*)d_in[15];
    const float* rel_att      = (const float*)d_in[16];
    const float* rel_msg      = (const float*)d_in[17];
    const float* skip         = (const float*)d_in[18];
    const float* rte_w        = (const float*)d_in[19];
    const float* rte_b        = (const float*)d_in[20];
    float* out = (float*)d_out;

    const size_t ND = (size_t)NN * 128;
    float* Qn      = (float*)d_ws;
    float* KV      = Qn + ND;               // 2*ND (k|v interleaved per row)
    float* rtab    = KV + 2 * ND;           // 240*256
    float* rproj   = rtab + 240 * 256;      // 240*128
    float* ktv     = rproj + 240 * 128;     // 720*256 (k|v interleaved)
    int*   cnt     = (int*)(ktv + 720 * 256);
    int*   fill    = cnt + NN;
    int*   row_st  = fill + NN;             // NN+1 (+pad)
    int*   edge_id = row_st + NN + 4;
    int*   order   = edge_id + EE;          // NN
    int*   tcnt    = order + NN;            // 3
    int*   fill3   = tcnt + 4;              // 3
    int2*  meta    = (int2*)(fill3 + 4);    // EE int2

    const int* esrc = edge_index;
    const int* etgt = edge_index + EE;

    // zero counters (cnt + fill contiguous; tcnt/fill3 separately)
    hipMemsetAsync(cnt, 0, 2 * NN * sizeof(int), stream);
    hipMemsetAsync(tcnt, 0, 8 * sizeof(int), stream);
    rte_tab_kernel<<<240, 256, 0, stream>>>(rtab);
    hist_kernel<<<(EE + 255) / 256, 256, 0, stream>>>(etgt, cnt);
    scan_kernel<<<1, 1024, 0, stream>>>(cnt, row_st);
    scatter_kernel<<<(EE + 255) / 256, 256, 0, stream>>>(etgt, row_st, fill, edge_id);
    edge_meta_kernel<<<(EE + 255) / 256, 256, 0, stream>>>(esrc, edge_type, edge_time,
                                                           node_type, edge_id, meta);
    node_hist_kernel<<<(NN + 255) / 256, 256, 0, stream>>>(node_type, tcnt);
    node_scatter_kernel<<<(NN + 255) / 256, 256, 0, stream>>>(node_type, tcnt, fill3, order);

    // input adaptation: x = tanh(typed_linear(node_feature))
    typed_lin_kernel<0><<<NN / 32, 256, 0, stream>>>(node_feature, node_type, order,
                                                     adapt_w, adapt_b, nullptr, out);

    for (int l = 0; l < 2; ++l) {
        const float* Wk_l = Wk + l * 49152;  const float* bk_l = bk + l * 384;
        const float* Wq_l = Wq + l * 49152;  const float* bq_l = bq + l * 384;
        const float* Wv_l = Wv + l * 49152;  const float* bv_l = bv + l * 384;
        const float* Wa_l = Wa + l * 49152;  const float* ba_l = ba + l * 384;
        const float* pri_l = rel_pri + l * 288;
        const float* att_l = rel_att + l * 8192;
        const float* msg_l = rel_msg + l * 8192;
        const float* skip_l = skip + l * 3;
        const float* rte_w_l = rte_w + l * 32768;
        const float* rte_b_l = rte_b + l * 128;

        rte_proj_kernel<<<240, 128, 0, stream>>>(rtab, rte_w_l, rte_b_l, rproj);
        ktv_kernel<<<720, 128, 0, stream>>>(rproj, Wk_l, Wv_l, ktv);
        qkv_kernel<<<NN / 32, 256, 0, stream>>>(out, node_type, order, Wq_l, bq_l,
                                                Wk_l, bk_l, Wv_l, bv_l, Qn, KV);
        attn_kernel<<<NN / 4, 256, 0, stream>>>(Qn, KV, ktv, node_type, meta,
                                                pri_l, att_l, msg_l, row_st,
                                                Qn /* h overwrites Qn: safe, row-local */);
        typed_lin_kernel<1><<<NN / 32, 256, 0, stream>>>(Qn, node_type, order, Wa_l, ba_l,
                                                         skip_l, out);
    }
}